// Round 4
// baseline (76.450 us; speedup 1.0000x reference)
//
#include <hip/hip_runtime.h>

// BiGNN fused MFMA kernel, R4.
// New vs R3: (1) feat tables pre-converted to bf16 in d_ws (halves gather
// bytes+loads, removes cvt from hot loop); (2) neighbor idx + BN consts in
// registers, no LDS in grouper loop except p-writes; (3) 4-row-deep gather
// pipelining. f32 fallback path if ws_size too small.

typedef __attribute__((ext_vector_type(8))) short short8;
typedef __attribute__((ext_vector_type(4))) float f32x4;

constexpr int N_ROWS = 50000;
constexpr int M1 = 200000, M2 = 100000;
constexpr int C1 = 32, C2 = 64, CL = 64, CG = 64;
constexpr float EPS = 1e-3f;
constexpr int RPB = 64, RPW = 16;

// ---- LDS layout (bytes) ----
constexpr int P_STRIDE = 136;                         // shorts/row (272B, 16B-aligned)
constexpr int P_BYTES  = 64 * P_STRIDE * 2;           // 17408
constexpr int ST_OFF   = P_BYTES;                     // 3 x 64 x float2 = 1536
constexpr int UN_OFF   = ST_OFF + 3 * 64 * 8;         // 18944
// phase A union: W1^T | W2^T
constexpr int W1_STRIDE = 40;                         // shorts (80B rows)
constexpr int W2_STRIDE = 72;                         // shorts (144B rows)
constexpr int W1_OFF   = UN_OFF;                      // 5120
constexpr int W2_OFF   = W1_OFF + 64 * W1_STRIDE * 2; // 9216 (ends 33280)
// phase B union: Wout^T
constexpr int WO_STRIDE = 200;                        // shorts (400B rows)
constexpr int WO_OFF   = UN_OFF;                      // 25600
constexpr int SMEM_BYTES = UN_OFF + 64 * WO_STRIDE * 2;  // 44544 -> 3 blocks/CU

__device__ __forceinline__ short f2bf(float f) {   // RNE via integer bit-trick
    unsigned u = __builtin_bit_cast(unsigned, f);
    unsigned r = u + 0x7fff + ((u >> 16) & 1);
    return (short)(r >> 16);
}
__device__ __forceinline__ short8 pack8(float4 x, float4 y) {
    short8 r;
    r[0] = f2bf(x.x); r[1] = f2bf(x.y); r[2] = f2bf(x.z); r[3] = f2bf(x.w);
    r[4] = f2bf(y.x); r[5] = f2bf(y.y); r[6] = f2bf(y.z); r[7] = f2bf(y.w);
    return r;
}
#define MFMA(a, b, c) __builtin_amdgcn_mfma_f32_16x16x32_bf16((a), (b), (c), 0, 0, 0)

// streaming f32 -> bf16 table conversion (groups of 8 elements)
__global__ __launch_bounds__(256)
void cvt_bf16(const float* __restrict__ src, short* __restrict__ dst, int n8) {
    for (int i = blockIdx.x * blockDim.x + threadIdx.x; i < n8;
         i += gridDim.x * blockDim.x) {
        const float4* p = (const float4*)(src + (size_t)i * 8);
        float4 a = p[0], b = p[1];
        *(short8*)(dst + (size_t)i * 8) = pack8(a, b);
    }
}

template<bool BF>
__global__ __launch_bounds__(256, 3)
void bignn_mfma(const float* __restrict__ feat_s1, const float* __restrict__ feat_s2,
                const float* __restrict__ feat_last,
                const float* __restrict__ Wg1, const float* __restrict__ bn_g1,
                const float* __restrict__ Wg2, const float* __restrict__ bn_g2,
                const float* __restrict__ Wout, const float* __restrict__ bn_out,
                const int* __restrict__ idx_s1, const int* __restrict__ idx_s2,
                const short* __restrict__ s1bf, const short* __restrict__ s2bf,
                float* __restrict__ out)
{
    __shared__ __align__(16) char smem[SMEM_BYTES];
    short* p_lds  = (short*)smem;                       // [64][P_STRIDE]
    float2* st    = (float2*)(smem + ST_OFF);           // [3][64] (s, t)
    short* w1t    = (short*)(smem + W1_OFF);            // [64][40]
    short* w2t    = (short*)(smem + W2_OFF);            // [64][72]
    short* wot    = (short*)(smem + WO_OFF);            // [64][200] (phase B)

    const int t    = threadIdx.x;
    const int lane = t & 63, lc = lane & 15, hi = lane >> 4;
    const int wave = t >> 6;
    const int row0 = blockIdx.x * RPB;
    const int rbase = row0 + wave * RPW;

    // ---- neighbor indices -> registers (issued before staging; independent)
    int nb1[RPW], nb2[RPW];
#pragma unroll
    for (int r = 0; r < RPW; ++r) {
        int grow = min(rbase + r, N_ROWS - 1);
        nb1[r] = idx_s1[(size_t)grow * 16 + lc];
        nb2[r] = idx_s2[(size_t)grow * 16 + lc];
    }

    // ---------------- phase A staging ----------------
    for (int e = t; e < C1 * CG; e += 256) {            // Wg1^T bf16
        int c = e >> 6, d = e & 63;
        w1t[d * W1_STRIDE + c] = f2bf(Wg1[e]);
    }
    for (int e = t; e < C2 * CG; e += 256) {            // Wg2^T bf16
        int c = e >> 6, d = e & 63;
        w2t[d * W2_STRIDE + c] = f2bf(Wg2[e]);
    }
    if (t < 192) {                                      // BN (s, t) per channel
        int which = t >> 6, ch = t & 63;
        const float* bnp = which == 0 ? bn_g1 : which == 1 ? bn_g2 : bn_out;
        float g = bnp[ch], b = bnp[64 + ch], m = bnp[128 + ch], v = bnp[192 + ch];
        float s = g * rsqrtf(v + EPS);
        st[which * 64 + ch] = make_float2(s, fmaf(-m, s, b));
    }
    __syncthreads();

    // B-frags register-resident (reused 16x per wave)
    short8 bW1[4], bW2[2][4];
#pragma unroll
    for (int nt = 0; nt < 4; ++nt)
        bW1[nt] = *(const short8*)(w1t + (nt * 16 + lc) * W1_STRIDE + hi * 8);
#pragma unroll
    for (int ck = 0; ck < 2; ++ck)
#pragma unroll
        for (int nt = 0; nt < 4; ++nt)
            bW2[ck][nt] = *(const short8*)(w2t + (nt * 16 + lc) * W2_STRIDE + ck * 32 + hi * 8);

    // BN consts -> registers
    float2 stg1[4], stg2[4];
#pragma unroll
    for (int nt = 0; nt < 4; ++nt) {
        stg1[nt] = st[nt * 16 + lc];
        stg2[nt] = st[64 + nt * 16 + lc];
    }

    // ---------------- grouper phase: 16 rows per wave, UN-deep pipeline ----
    constexpr int UN = BF ? 4 : 2;
#pragma unroll 1
    for (int rb = 0; rb < RPW; rb += UN) {
        short8 A1[UN], A2a[UN], A2b[UN];
#pragma unroll
        for (int u = 0; u < UN; ++u) {
            if constexpr (BF) {
                A1[u]  = *(const short8*)(s1bf + (size_t)nb1[rb + u] * C1 + hi * 8);
                A2a[u] = *(const short8*)(s2bf + (size_t)nb2[rb + u] * C2 + hi * 8);
                A2b[u] = *(const short8*)(s2bf + (size_t)nb2[rb + u] * C2 + 32 + hi * 8);
            } else {
                const float4* g1p = (const float4*)(feat_s1 + (size_t)nb1[rb + u] * C1 + hi * 8);
                A1[u] = pack8(g1p[0], g1p[1]);
                const float4* g2p = (const float4*)(feat_s2 + (size_t)nb2[rb + u] * C2 + hi * 8);
                A2a[u] = pack8(g2p[0], g2p[1]);
                const float4* g2q = (const float4*)(feat_s2 + (size_t)nb2[rb + u] * C2 + 32 + hi * 8);
                A2b[u] = pack8(g2q[0], g2q[1]);
            }
        }
#pragma unroll
        for (int u = 0; u < UN; ++u) {
            const int r = wave * RPW + rb + u;          // local row
            f32x4 z = {0.f, 0.f, 0.f, 0.f};
            f32x4 acc1[4], acc2[4];
#pragma unroll
            for (int nt = 0; nt < 4; ++nt) acc1[nt] = MFMA(A1[u], bW1[nt], z);
#pragma unroll
            for (int nt = 0; nt < 4; ++nt) acc2[nt] = MFMA(A2a[u], bW2[0][nt], z);
#pragma unroll
            for (int nt = 0; nt < 4; ++nt) acc2[nt] = MFMA(A2b[u], bW2[1][nt], acc2[nt]);

            // fused BN+ReLU+maxpool: max_k relu(s*h+t) = relu(|s|*max_k(sgn(s)h)+t)
            float pv1[4], pv2[4];
#pragma unroll
            for (int nt = 0; nt < 4; ++nt) {
                float2 s1 = stg1[nt];
                f32x4 a = acc1[nt];
                float m0 = s1.x >= 0.f ? a[0] : -a[0];
                float m1 = s1.x >= 0.f ? a[1] : -a[1];
                float m2 = s1.x >= 0.f ? a[2] : -a[2];
                float m3 = s1.x >= 0.f ? a[3] : -a[3];
                float m = fmaxf(fmaxf(m0, m1), fmaxf(m2, m3));
                m = fmaxf(m, __shfl_xor(m, 16));
                m = fmaxf(m, __shfl_xor(m, 32));
                pv1[nt] = fmaxf(0.f, fmaf(fabsf(s1.x), m, s1.y));

                float2 s2 = stg2[nt];
                f32x4 b = acc2[nt];
                float n0 = s2.x >= 0.f ? b[0] : -b[0];
                float n1 = s2.x >= 0.f ? b[1] : -b[1];
                float n2 = s2.x >= 0.f ? b[2] : -b[2];
                float n3 = s2.x >= 0.f ? b[3] : -b[3];
                float n = fmaxf(fmaxf(n0, n1), fmaxf(n2, n3));
                n = fmaxf(n, __shfl_xor(n, 16));
                n = fmaxf(n, __shfl_xor(n, 32));
                pv2[nt] = fmaxf(0.f, fmaf(fabsf(s2.x), n, s2.y));
            }
            float w1v = hi == 0 ? pv1[0] : hi == 1 ? pv1[1] : hi == 2 ? pv1[2] : pv1[3];
            float w2v = hi == 0 ? pv2[0] : hi == 1 ? pv2[1] : hi == 2 ? pv2[2] : pv2[3];
            p_lds[r * P_STRIDE + hi * 16 + lc]      = f2bf(w1v);
            p_lds[r * P_STRIDE + 64 + hi * 16 + lc] = f2bf(w2v);
        }
    }
    __syncthreads();

    // ---------------- stage Wout^T bf16 (phase B union) ----------------
    for (int e = t; e < (CL + 2 * CG) * CG; e += 256) {  // 192*64
        int c = e >> 6, d = e & 63;
        wot[d * WO_STRIDE + c] = f2bf(Wout[e]);
    }
    __syncthreads();

    // ---------------- final layer: 16-row M-tile per wave ----------------
    const int tile0 = rbase;
    {
        const int mrow = min(tile0 + lc, N_ROWS - 1);
        const float4* flp = (const float4*)(feat_last + (size_t)mrow * CL + hi * 8);
        float4 f0 = flp[0], f1 = flp[1];
        const float4* flq = (const float4*)(feat_last + (size_t)mrow * CL + 32 + hi * 8);
        float4 f2 = flq[0], f3 = flq[1];
        short8 aA = pack8(f0, f1), aB = pack8(f2, f3);

        f32x4 facc[4] = {{0.f,0.f,0.f,0.f},{0.f,0.f,0.f,0.f},{0.f,0.f,0.f,0.f},{0.f,0.f,0.f,0.f}};
#pragma unroll
        for (int ck = 0; ck < 6; ++ck) {
            short8 af;
            if (ck == 0) af = aA;
            else if (ck == 1) af = aB;
            else af = *(const short8*)(p_lds + (wave * RPW + lc) * P_STRIDE + (ck - 2) * 32 + hi * 8);
#pragma unroll
            for (int nt = 0; nt < 4; ++nt) {
                short8 bf = *(const short8*)(wot + (nt * 16 + lc) * WO_STRIDE + ck * 32 + hi * 8);
                facc[nt] = MFMA(af, bf, facc[nt]);
            }
        }
#pragma unroll
        for (int nt = 0; nt < 4; ++nt) {
            float2 so = st[2 * 64 + nt * 16 + lc];
#pragma unroll
            for (int rg = 0; rg < 4; ++rg) {
                int grow = tile0 + hi * 4 + rg;
                if (grow < N_ROWS) {
                    float v = fmaxf(0.f, fmaf(so.x, facc[nt][rg], so.y));
                    out[(size_t)grow * CG + nt * 16 + lc] = v;
                }
            }
        }
    }
}

extern "C" void kernel_launch(void* const* d_in, const int* in_sizes, int n_in,
                              void* d_out, int out_size, void* d_ws, size_t ws_size,
                              hipStream_t stream) {
    const float* feat_s1   = (const float*)d_in[0];
    const float* feat_s2   = (const float*)d_in[1];
    const float* feat_last = (const float*)d_in[2];
    const float* Wg1       = (const float*)d_in[3];
    const float* bn_g1     = (const float*)d_in[4];
    const float* Wg2       = (const float*)d_in[5];
    const float* bn_g2     = (const float*)d_in[6];
    const float* Wout      = (const float*)d_in[7];
    const float* bn_out    = (const float*)d_in[8];
    const int*   idx_s1    = (const int*)d_in[9];
    const int*   idx_s2    = (const int*)d_in[10];
    float* out = (float*)d_out;

    const size_t need = ((size_t)M1 * C1 + (size_t)M2 * C2) * sizeof(short); // 25.6 MB
    dim3 grid((N_ROWS + RPB - 1) / RPB);

    if (ws_size >= need) {
        short* s1bf = (short*)d_ws;
        short* s2bf = s1bf + (size_t)M1 * C1;
        cvt_bf16<<<2048, 256, 0, stream>>>(feat_s1, s1bf, M1 * C1 / 8);
        cvt_bf16<<<2048, 256, 0, stream>>>(feat_s2, s2bf, M2 * C2 / 8);
        bignn_mfma<true><<<grid, dim3(256), 0, stream>>>(
            feat_s1, feat_s2, feat_last, Wg1, bn_g1, Wg2, bn_g2, Wout, bn_out,
            idx_s1, idx_s2, s1bf, s2bf, out);
    } else {
        bignn_mfma<false><<<grid, dim3(256), 0, stream>>>(
            feat_s1, feat_s2, feat_last, Wg1, bn_g1, Wg2, bn_g2, Wout, bn_out,
            idx_s1, idx_s2, nullptr, nullptr, out);
    }
}

// Round 5
// 64.739 us; speedup vs baseline: 1.1809x; 1.1809x over previous
//
#include <hip/hip_runtime.h>

// BiGNN fused MFMA kernel, R5.
// vs R4: (1) double-buffered 4-row gather pipeline (steady ~24 loads in
// flight/wave); (2) persistent blocks + atomic tile stealing (no grid tail,
// weights staged once per block); (3) no barriers in the tile loop except the
// tile broadcast (p_lds is wave-private); BN consts in registers.

typedef __attribute__((ext_vector_type(8))) short short8;
typedef __attribute__((ext_vector_type(4))) float f32x4;

constexpr int N_ROWS = 50000;
constexpr int M1 = 200000, M2 = 100000;
constexpr int C1 = 32, C2 = 64, CL = 64, CG = 64;
constexpr float EPS = 1e-3f;
constexpr int RPB = 64, RPW = 16;
constexpr int N_TILES = (N_ROWS + RPB - 1) / RPB;     // 782

// ---- LDS layout (bytes) ----
constexpr int P_STRIDE = 136;                         // shorts/row (272B, 16B-aligned)
constexpr int P_BYTES  = 64 * P_STRIDE * 2;           // 17408
constexpr int ST_OFF   = P_BYTES;                     // 3 x 64 x float2 = 1536
constexpr int UN_OFF   = ST_OFF + 3 * 64 * 8;         // 18944
// phase A union: W1^T | W2^T  (then overwritten by Wout^T)
constexpr int W1_STRIDE = 40;                         // shorts (80B rows)
constexpr int W2_STRIDE = 72;                         // shorts (144B rows)
constexpr int W1_OFF   = UN_OFF;
constexpr int W2_OFF   = W1_OFF + 64 * W1_STRIDE * 2;
// phase B union member:
constexpr int WO_STRIDE = 200;                        // shorts (400B rows)
constexpr int WO_OFF   = UN_OFF;
constexpr int SMEM_BYTES = UN_OFF + 64 * WO_STRIDE * 2;  // 44544

// workspace layout
constexpr size_t S1_ELEMS = (size_t)M1 * C1;
constexpr size_t S2_ELEMS = (size_t)M2 * C2;
constexpr size_t CNT_OFF  = (S1_ELEMS + S2_ELEMS) * sizeof(short);  // 25.6e6, 256-aligned
constexpr size_t WS_NEED  = CNT_OFF + 256;

__device__ __forceinline__ short f2bf(float f) {   // RNE via integer bit-trick
    unsigned u = __builtin_bit_cast(unsigned, f);
    unsigned r = u + 0x7fff + ((u >> 16) & 1);
    return (short)(r >> 16);
}
__device__ __forceinline__ short8 pack8(float4 x, float4 y) {
    short8 r;
    r[0] = f2bf(x.x); r[1] = f2bf(x.y); r[2] = f2bf(x.z); r[3] = f2bf(x.w);
    r[4] = f2bf(y.x); r[5] = f2bf(y.y); r[6] = f2bf(y.z); r[7] = f2bf(y.w);
    return r;
}
#define MFMA(a, b, c) __builtin_amdgcn_mfma_f32_16x16x32_bf16((a), (b), (c), 0, 0, 0)

// streaming f32 -> bf16 conversion for both tables + counter zeroing
__global__ __launch_bounds__(256)
void cvt_bf16(const float* __restrict__ s1, short* __restrict__ d1, int n1_8,
              const float* __restrict__ s2, short* __restrict__ d2, int n2_8,
              int* __restrict__ cnt) {
    if (blockIdx.x == 0 && threadIdx.x == 0) *cnt = 0;
    for (int i = blockIdx.x * blockDim.x + threadIdx.x; i < n1_8 + n2_8;
         i += gridDim.x * blockDim.x) {
        const float* src = i < n1_8 ? s1 + (size_t)i * 8 : s2 + (size_t)(i - n1_8) * 8;
        short* dst = i < n1_8 ? d1 + (size_t)i * 8 : d2 + (size_t)(i - n1_8) * 8;
        const float4* p = (const float4*)src;
        *(short8*)dst = pack8(p[0], p[1]);
    }
}

// load a 4-row gather chunk into register buffers (literal RB at call sites)
#define LOAD_CHUNK(RB, B1, B2a, B2b)                                           \
    _Pragma("unroll")                                                          \
    for (int u = 0; u < 4; ++u) {                                              \
        if constexpr (BF) {                                                    \
            B1[u]  = *(const short8*)(s1bf + (size_t)nb1[(RB)+u] * C1 + hi*8); \
            B2a[u] = *(const short8*)(s2bf + (size_t)nb2[(RB)+u] * C2 + hi*8); \
            B2b[u] = *(const short8*)(s2bf + (size_t)nb2[(RB)+u] * C2 + 32 + hi*8); \
        } else {                                                               \
            const float4* g1p = (const float4*)(feat_s1 + (size_t)nb1[(RB)+u] * C1 + hi*8); \
            B1[u] = pack8(g1p[0], g1p[1]);                                     \
            const float4* g2p = (const float4*)(feat_s2 + (size_t)nb2[(RB)+u] * C2 + hi*8); \
            B2a[u] = pack8(g2p[0], g2p[1]);                                    \
            const float4* g2q = (const float4*)(feat_s2 + (size_t)nb2[(RB)+u] * C2 + 32 + hi*8); \
            B2b[u] = pack8(g2q[0], g2q[1]);                                    \
        }                                                                      \
    }

// consume a 4-row chunk: 12 MFMA + fused BN/ReLU/maxpool + p_lds writes
#define COMP_CHUNK(RB, B1, B2a, B2b)                                           \
    _Pragma("unroll")                                                          \
    for (int u = 0; u < 4; ++u) {                                              \
        const int r_ = wave * RPW + (RB) + u;                                  \
        f32x4 z_ = {0.f, 0.f, 0.f, 0.f};                                       \
        f32x4 acc1[4], acc2[4];                                                \
        _Pragma("unroll")                                                      \
        for (int nt = 0; nt < 4; ++nt) acc1[nt] = MFMA(B1[u], bW1[nt], z_);    \
        _Pragma("unroll")                                                      \
        for (int nt = 0; nt < 4; ++nt) acc2[nt] = MFMA(B2a[u], bW2[0][nt], z_);\
        _Pragma("unroll")                                                      \
        for (int nt = 0; nt < 4; ++nt) acc2[nt] = MFMA(B2b[u], bW2[1][nt], acc2[nt]); \
        float pv1[4], pv2[4];                                                  \
        _Pragma("unroll")                                                      \
        for (int nt = 0; nt < 4; ++nt) {                                       \
            float2 s1_ = stg1[nt]; f32x4 a_ = acc1[nt];                        \
            float m0 = s1_.x >= 0.f ? a_[0] : -a_[0];                          \
            float m1 = s1_.x >= 0.f ? a_[1] : -a_[1];                          \
            float m2 = s1_.x >= 0.f ? a_[2] : -a_[2];                          \
            float m3 = s1_.x >= 0.f ? a_[3] : -a_[3];                          \
            float m_ = fmaxf(fmaxf(m0, m1), fmaxf(m2, m3));                    \
            m_ = fmaxf(m_, __shfl_xor(m_, 16));                                \
            m_ = fmaxf(m_, __shfl_xor(m_, 32));                                \
            pv1[nt] = fmaxf(0.f, fmaf(fabsf(s1_.x), m_, s1_.y));               \
            float2 s2_ = stg2[nt]; f32x4 b_ = acc2[nt];                        \
            float n0 = s2_.x >= 0.f ? b_[0] : -b_[0];                          \
            float n1 = s2_.x >= 0.f ? b_[1] : -b_[1];                          \
            float n2 = s2_.x >= 0.f ? b_[2] : -b_[2];                          \
            float n3 = s2_.x >= 0.f ? b_[3] : -b_[3];                          \
            float n_ = fmaxf(fmaxf(n0, n1), fmaxf(n2, n3));                    \
            n_ = fmaxf(n_, __shfl_xor(n_, 16));                                \
            n_ = fmaxf(n_, __shfl_xor(n_, 32));                                \
            pv2[nt] = fmaxf(0.f, fmaf(fabsf(s2_.x), n_, s2_.y));               \
        }                                                                      \
        float w1v = hi == 0 ? pv1[0] : hi == 1 ? pv1[1] : hi == 2 ? pv1[2] : pv1[3]; \
        float w2v = hi == 0 ? pv2[0] : hi == 1 ? pv2[1] : hi == 2 ? pv2[2] : pv2[3]; \
        p_lds[r_ * P_STRIDE + hi * 16 + lc]      = f2bf(w1v);                  \
        p_lds[r_ * P_STRIDE + 64 + hi * 16 + lc] = f2bf(w2v);                  \
    }

template<bool BF>
__global__ __launch_bounds__(256, 2)
void bignn_mfma(const float* __restrict__ feat_s1, const float* __restrict__ feat_s2,
                const float* __restrict__ feat_last,
                const float* __restrict__ Wg1, const float* __restrict__ bn_g1,
                const float* __restrict__ Wg2, const float* __restrict__ bn_g2,
                const float* __restrict__ Wout, const float* __restrict__ bn_out,
                const int* __restrict__ idx_s1, const int* __restrict__ idx_s2,
                const short* __restrict__ s1bf, const short* __restrict__ s2bf,
                int* __restrict__ cnt, float* __restrict__ out)
{
    __shared__ __align__(16) char smem[SMEM_BYTES];
    __shared__ int s_tile;
    short* p_lds  = (short*)smem;                       // [64][P_STRIDE]
    float2* st    = (float2*)(smem + ST_OFF);           // [3][64] (s, t)
    short* w1t    = (short*)(smem + W1_OFF);            // [64][40]
    short* w2t    = (short*)(smem + W2_OFF);            // [64][72]
    short* wot    = (short*)(smem + WO_OFF);            // [64][200] (after re-stage)

    const int t    = threadIdx.x;
    const int lane = t & 63, lc = lane & 15, hi = lane >> 4;
    const int wave = t >> 6;

    // ---------------- one-time staging ----------------
    for (int e = t; e < C1 * CG; e += 256) {            // Wg1^T bf16
        int c = e >> 6, d = e & 63;
        w1t[d * W1_STRIDE + c] = f2bf(Wg1[e]);
    }
    for (int e = t; e < C2 * CG; e += 256) {            // Wg2^T bf16
        int c = e >> 6, d = e & 63;
        w2t[d * W2_STRIDE + c] = f2bf(Wg2[e]);
    }
    if (t < 192) {                                      // BN (s, t) per channel
        int which = t >> 6, ch = t & 63;
        const float* bnp = which == 0 ? bn_g1 : which == 1 ? bn_g2 : bn_out;
        float g = bnp[ch], b = bnp[64 + ch], m = bnp[128 + ch], v = bnp[192 + ch];
        float s = g * rsqrtf(v + EPS);
        st[which * 64 + ch] = make_float2(s, fmaf(-m, s, b));
    }
    __syncthreads();

    // register-resident B-frags + BN consts
    short8 bW1[4], bW2[2][4];
#pragma unroll
    for (int nt = 0; nt < 4; ++nt)
        bW1[nt] = *(const short8*)(w1t + (nt * 16 + lc) * W1_STRIDE + hi * 8);
#pragma unroll
    for (int ck = 0; ck < 2; ++ck)
#pragma unroll
        for (int nt = 0; nt < 4; ++nt)
            bW2[ck][nt] = *(const short8*)(w2t + (nt * 16 + lc) * W2_STRIDE + ck * 32 + hi * 8);
    float2 stg1[4], stg2[4], stgo[4];
#pragma unroll
    for (int nt = 0; nt < 4; ++nt) {
        stg1[nt] = st[nt * 16 + lc];
        stg2[nt] = st[64 + nt * 16 + lc];
        stgo[nt] = st[128 + nt * 16 + lc];
    }
    __syncthreads();                                    // all reads of w1t/w2t done

    for (int e = t; e < (CL + 2 * CG) * CG; e += 256) { // Wout^T bf16 (overwrites w1t/w2t)
        int c = e >> 6, d = e & 63;
        wot[d * WO_STRIDE + c] = f2bf(Wout[e]);
    }
    __syncthreads();

    // ---------------- persistent tile loop ----------------
    for (;;) {
        int tile;
        if constexpr (BF) {
            if (t == 0) s_tile = atomicAdd(cnt, 1);
            __syncthreads();
            tile = s_tile;
            __syncthreads();
            if (tile >= N_TILES) break;
        } else {
            tile = blockIdx.x;
        }

        const int rbase = tile * RPB + wave * RPW;

        // neighbor indices -> registers
        int nb1[RPW], nb2[RPW];
#pragma unroll
        for (int r = 0; r < RPW; ++r) {
            int grow = min(rbase + r, N_ROWS - 1);
            nb1[r] = idx_s1[(size_t)grow * 16 + lc];
            nb2[r] = idx_s2[(size_t)grow * 16 + lc];
        }

        // double-buffered 4-row chunks: steady ~24 loads in flight
        short8 A1a[4], A2aa[4], A2ba[4];
        short8 A1b[4], A2ab[4], A2bb[4];
        LOAD_CHUNK(0, A1a, A2aa, A2ba);
        LOAD_CHUNK(4, A1b, A2ab, A2bb);
        COMP_CHUNK(0, A1a, A2aa, A2ba);
        LOAD_CHUNK(8, A1a, A2aa, A2ba);
        COMP_CHUNK(4, A1b, A2ab, A2bb);
        LOAD_CHUNK(12, A1b, A2ab, A2bb);
        COMP_CHUNK(8, A1a, A2aa, A2ba);
        COMP_CHUNK(12, A1b, A2ab, A2bb);

        // -------- final layer: 16-row M-tile per wave (wave-private p_lds) --------
        {
            const int mrow = min(rbase + lc, N_ROWS - 1);
            const float4* flp = (const float4*)(feat_last + (size_t)mrow * CL + hi * 8);
            float4 f0 = flp[0], f1 = flp[1];
            const float4* flq = (const float4*)(feat_last + (size_t)mrow * CL + 32 + hi * 8);
            float4 f2 = flq[0], f3 = flq[1];
            short8 aA = pack8(f0, f1), aB = pack8(f2, f3);

            f32x4 facc[4] = {{0.f,0.f,0.f,0.f},{0.f,0.f,0.f,0.f},{0.f,0.f,0.f,0.f},{0.f,0.f,0.f,0.f}};
#pragma unroll
            for (int ck = 0; ck < 6; ++ck) {
                short8 af;
                if (ck == 0) af = aA;
                else if (ck == 1) af = aB;
                else af = *(const short8*)(p_lds + (wave * RPW + lc) * P_STRIDE + (ck - 2) * 32 + hi * 8);
#pragma unroll
                for (int nt = 0; nt < 4; ++nt) {
                    short8 bf = *(const short8*)(wot + (nt * 16 + lc) * WO_STRIDE + ck * 32 + hi * 8);
                    facc[nt] = MFMA(af, bf, facc[nt]);
                }
            }
#pragma unroll
            for (int nt = 0; nt < 4; ++nt) {
                float2 so = stgo[nt];
#pragma unroll
                for (int rg = 0; rg < 4; ++rg) {
                    int grow = rbase + hi * 4 + rg;
                    if (grow < N_ROWS) {
                        float v = fmaxf(0.f, fmaf(so.x, facc[nt][rg], so.y));
                        out[(size_t)grow * CG + nt * 16 + lc] = v;
                    }
                }
            }
        }
        if constexpr (!BF) break;
    }
}

extern "C" void kernel_launch(void* const* d_in, const int* in_sizes, int n_in,
                              void* d_out, int out_size, void* d_ws, size_t ws_size,
                              hipStream_t stream) {
    const float* feat_s1   = (const float*)d_in[0];
    const float* feat_s2   = (const float*)d_in[1];
    const float* feat_last = (const float*)d_in[2];
    const float* Wg1       = (const float*)d_in[3];
    const float* bn_g1     = (const float*)d_in[4];
    const float* Wg2       = (const float*)d_in[5];
    const float* bn_g2     = (const float*)d_in[6];
    const float* Wout      = (const float*)d_in[7];
    const float* bn_out    = (const float*)d_in[8];
    const int*   idx_s1    = (const int*)d_in[9];
    const int*   idx_s2    = (const int*)d_in[10];
    float* out = (float*)d_out;

    if (ws_size >= WS_NEED) {
        short* s1bf = (short*)d_ws;
        short* s2bf = s1bf + S1_ELEMS;
        int*   cnt  = (int*)((char*)d_ws + CNT_OFF);
        cvt_bf16<<<2048, 256, 0, stream>>>(feat_s1, s1bf, (int)(S1_ELEMS / 8),
                                           feat_s2, s2bf, (int)(S2_ELEMS / 8), cnt);
        bignn_mfma<true><<<768, dim3(256), 0, stream>>>(
            feat_s1, feat_s2, feat_last, Wg1, bn_g1, Wg2, bn_g2, Wout, bn_out,
            idx_s1, idx_s2, s1bf, s2bf, cnt, out);
    } else {
        bignn_mfma<false><<<N_TILES, dim3(256), 0, stream>>>(
            feat_s1, feat_s2, feat_last, Wg1, bn_g1, Wg2, bn_g2, Wout, bn_out,
            idx_s1, idx_s2, nullptr, nullptr, nullptr, out);
    }
}